// Round 18
// baseline (223.073 us; speedup 1.0000x reference)
//
#include <hip/hip_runtime.h>
#include <hip/hip_bf16.h>

#define D_MODEL 1536
#define NEXP    64
#define D_HID   512
#define NTOK    4096
#define NT1     (D_MODEL / 64)   // 24 K-steps
#define NT2     (D_HID / 64)     // 8 K-steps
#define MT      192              // packed M rows per block pass

typedef __attribute__((ext_vector_type(8))) short short8;
typedef __attribute__((ext_vector_type(4))) float f32x4;

__device__ __forceinline__ unsigned short f2bf(float f) {
  unsigned u = __builtin_bit_cast(unsigned, f);
  u += 0x7FFFu + ((u >> 16) & 1u);
  return (unsigned short)(u >> 16);
}
__device__ __forceinline__ unsigned pk2(float a, float b) {
  return (unsigned)f2bf(a) | ((unsigned)f2bf(b) << 16);
}
__device__ __forceinline__ float bf2f(unsigned short u) {
  return __builtin_bit_cast(float, ((unsigned)u) << 16);
}

__device__ __forceinline__ void gl16(const void* g, void* s) {
  __builtin_amdgcn_global_load_lds(
      (const __attribute__((address_space(1))) unsigned int*)g,
      (__attribute__((address_space(3))) unsigned int*)s, 16, 0, 0);
}

#define WAITV(N)  asm volatile("s_waitcnt vmcnt(" #N ")" ::: "memory")
#define WAITL0    asm volatile("s_waitcnt lgkmcnt(0)" ::: "memory")
#define SBAR      __builtin_amdgcn_s_barrier()
#define SCHED0    __builtin_amdgcn_sched_barrier(0)

// ---------------- utility ----------------

__global__ void zero_small_kernel(int* __restrict__ counts) {
  counts[threadIdx.x] = 0;
}

// ---------------- split conversion: x -> (xhi, xlo), Wr -> (whi, wlo) ----------------

__global__ __launch_bounds__(256) void cvt_split_kernel(const float* __restrict__ x,
    const float* __restrict__ Wr,
    unsigned short* __restrict__ xhi, unsigned short* __restrict__ xlo,
    unsigned short* __restrict__ whi, unsigned short* __restrict__ wlo)
{
  const float* src; unsigned short* dhi; unsigned short* dlo; long i;
  long bid = blockIdx.x;
  if (bid < 3072) { src = x;  dhi = xhi; dlo = xlo; i = (bid * 256 + threadIdx.x) * 8; }
  else            { src = Wr; dhi = whi; dlo = wlo; i = ((bid - 3072) * 256 + threadIdx.x) * 8; }
  float4 a = *(const float4*)(src + i);
  float4 b = *(const float4*)(src + i + 4);
  float f[8] = {a.x, a.y, a.z, a.w, b.x, b.y, b.z, b.w};
  unsigned short h[8], l[8];
  #pragma unroll
  for (int j = 0; j < 8; ++j) {
    h[j] = f2bf(f[j]);
    l[j] = f2bf(f[j] - bf2f(h[j]));
  }
  uint4 ph, pl;
  ph.x = (unsigned)h[0] | ((unsigned)h[1] << 16);
  ph.y = (unsigned)h[2] | ((unsigned)h[3] << 16);
  ph.z = (unsigned)h[4] | ((unsigned)h[5] << 16);
  ph.w = (unsigned)h[6] | ((unsigned)h[7] << 16);
  pl.x = (unsigned)l[0] | ((unsigned)l[1] << 16);
  pl.y = (unsigned)l[2] | ((unsigned)l[3] << 16);
  pl.z = (unsigned)l[4] | ((unsigned)l[5] << 16);
  pl.w = (unsigned)l[6] | ((unsigned)l[7] << 16);
  *(uint4*)(dhi + i) = ph;
  *(uint4*)(dlo + i) = pl;
}

// ---------------- router v5: split-bf16 MFMA GEMM + in-kernel top-2 ----------------

__global__ __launch_bounds__(256) void router_kernel(
    const unsigned short* __restrict__ xhi, const unsigned short* __restrict__ xlo,
    const unsigned short* __restrict__ whi, const unsigned short* __restrict__ wlo,
    int* __restrict__ topidx, float* __restrict__ topw, int* __restrict__ counts)
{
  __shared__ unsigned short lds[8 * 4096];
  const int tid  = threadIdx.x;
  const int lane = tid & 63;
  const int wv   = tid >> 6;
  const int t0   = blockIdx.x * 64;

  const int lslot = (lane & 7) ^ (lane >> 3);
  const unsigned short* gsrc[4][2];
  #pragma unroll
  for (int j = 0; j < 2; ++j) {
    int r = (wv * 2 + j) * 8 + (lane >> 3);
    gsrc[0][j] = xhi + (long)(t0 + r) * D_MODEL + lslot * 8;
    gsrc[1][j] = xlo + (long)(t0 + r) * D_MODEL + lslot * 8;
    gsrc[2][j] = whi + (long)r * D_MODEL + lslot * 8;
    gsrc[3][j] = wlo + (long)r * D_MODEL + lslot * 8;
  }

  auto ISSUE = [&](int t, int b) {
    const int k0 = t * 64;
    SCHED0;
    #pragma unroll
    for (int tile = 0; tile < 4; ++tile)
      #pragma unroll
      for (int j = 0; j < 2; ++j)
        gl16(gsrc[tile][j] + k0, &lds[(b * 4 + tile) * 4096 + (wv * 2 + j) * 512]);
    SCHED0;
  };

  f32x4 acc[4];
  #pragma unroll
  for (int i = 0; i < 4; ++i) acc[i] = (f32x4)0.f;

  const int arow = wv * 16 + (lane & 15);

  auto COMPUTE = [&](int b) {
    const unsigned short* Ah = &lds[(b * 4 + 0) * 4096];
    const unsigned short* Al = &lds[(b * 4 + 1) * 4096];
    const unsigned short* Bh = &lds[(b * 4 + 2) * 4096];
    const unsigned short* Bl = &lds[(b * 4 + 3) * 4096];
    #pragma unroll
    for (int ks = 0; ks < 2; ++ks) {
      int pa = (ks * 4 + (lane >> 4)) ^ (arow & 7);
      short8 ah = *(const short8*)(Ah + arow * 64 + pa * 8);
      short8 al = *(const short8*)(Al + arow * 64 + pa * 8);
      short8 bh[4], bl[4];
      #pragma unroll
      for (int ni = 0; ni < 4; ++ni) {
        int br = ni * 16 + (lane & 15);
        int pb = (ks * 4 + (lane >> 4)) ^ (br & 7);
        bh[ni] = *(const short8*)(Bh + br * 64 + pb * 8);
        bl[ni] = *(const short8*)(Bl + br * 64 + pb * 8);
      }
      __builtin_amdgcn_s_setprio(1);
      #pragma unroll
      for (int ni = 0; ni < 4; ++ni) {
        acc[ni] = __builtin_amdgcn_mfma_f32_16x16x32_bf16(ah, bh[ni], acc[ni], 0, 0, 0);
        acc[ni] = __builtin_amdgcn_mfma_f32_16x16x32_bf16(ah, bl[ni], acc[ni], 0, 0, 0);
        acc[ni] = __builtin_amdgcn_mfma_f32_16x16x32_bf16(al, bh[ni], acc[ni], 0, 0, 0);
      }
      __builtin_amdgcn_s_setprio(0);
    }
  };

  ISSUE(0, 0);
  ISSUE(1, 1);
  WAITV(8);
  SBAR;

  #pragma unroll 1
  for (int t = 0; t < NT1; t += 2) {
    COMPUTE(0);
    SBAR;
    if (t + 2 < NT1) { ISSUE(t + 2, 0); WAITV(8); }
    else             { WAITV(0); }
    SBAR;
    COMPUTE(1);
    SBAR;
    if (t + 2 < NT1) {
      if (t + 3 < NT1) { ISSUE(t + 3, 1); WAITV(8); }
      else             { WAITV(0); }
      SBAR;
    }
  }

  float* lgl = (float*)lds;           // [64][66]
  #pragma unroll
  for (int ni = 0; ni < 4; ++ni)
    #pragma unroll
    for (int rg = 0; rg < 4; ++rg) {
      int tok = wv * 16 + (lane >> 4) * 4 + rg;
      int e   = ni * 16 + (lane & 15);
      lgl[tok * 66 + e] = acc[ni][rg];
    }
  __syncthreads();

  for (int i = 0; i < 16; ++i) {
    const int tl = wv * 16 + i;
    float v = lgl[tl * 66 + lane];
    float v0 = v; int e0 = lane;
    #pragma unroll
    for (int off = 32; off > 0; off >>= 1) {
      float ov = __shfl_xor(v0, off);
      int   oe = __shfl_xor(e0, off);
      if (ov > v0 || (ov == v0 && oe < e0)) { v0 = ov; e0 = oe; }
    }
    float v1 = (lane == e0) ? -3.0e38f : v;
    int e1 = lane;
    #pragma unroll
    for (int off = 32; off > 0; off >>= 1) {
      float ov = __shfl_xor(v1, off);
      int   oe = __shfl_xor(e1, off);
      if (ov > v1 || (ov == v1 && oe < e1)) { v1 = ov; e1 = oe; }
    }
    if (lane == 0) {
      int tt = t0 + tl;
      float w0 = 1.f / (1.f + expf(v1 - v0));
      topidx[tt * 2]     = e0;
      topidx[tt * 2 + 1] = e1;
      topw[tt * 2]       = w0;
      topw[tt * 2 + 1]   = 1.f - w0;
      atomicAdd(&counts[e0], 1);
      atomicAdd(&counts[e1], 1);
    }
  }
}

// ---------------- scan + scatter ----------------

__global__ void scan_kernel(const int* __restrict__ counts, int* __restrict__ offs,
                            int* __restrict__ cursor)
{
  int e = threadIdx.x;
  int c = counts[e];
  int xx = c;
  #pragma unroll
  for (int off = 1; off < 64; off <<= 1) {
    int y = __shfl_up(xx, off);
    if (e >= off) xx += y;
  }
  offs[e + 1] = xx;
  if (e == 0) offs[0] = 0;
  cursor[e] = 0;
}

__global__ void scatter_kernel(const int* __restrict__ topidx, const float* __restrict__ topw,
    const int* __restrict__ offs, int* __restrict__ cursor,
    int* __restrict__ perm, float* __restrict__ wgt, int* __restrict__ tok2slot)
{
  int t = blockIdx.x * blockDim.x + threadIdx.x;
  if (t >= NTOK) return;
  #pragma unroll
  for (int k = 0; k < 2; ++k) {
    int e = topidx[t * 2 + k];
    float w = topw[t * 2 + k];
    int pos = atomicAdd(&cursor[e], 1);
    int slot = offs[e] + pos;
    perm[slot] = t;
    wgt[slot] = w;
    tok2slot[t * 2 + k] = slot;
  }
}

// ---- pipelined step: B-stream 3 tiles deep (3 breg sets), A (gl16) 2 deep ----
#define FS(T, AB, BRI, BRW, KNT)                                   \
  {                                                                \
    COMPUTE(Abuf[AB], Bbuf[AB]);                                   \
    SBAR;                                                          \
    if ((T) + 2 < (KNT)) ISSUEA((T) + 2, Abuf[AB]);                \
    if ((T) + 3 < (KNT)) ISSUEB((T) + 3, BRI);                     \
    if ((T) + 3 < (KNT))      { WAITV(14); }                       \
    else if ((T) + 2 < (KNT)) { WAITV(10); }                       \
    else                      { WAITV(0);  }                       \
    if ((T) + 1 < (KNT)) { WRITE_B(BRW, Bbuf[(AB) ^ 1]); WAITL0; } \
    SBAR;                                                          \
  }

// ---------------- ffn1: 256-thread, B depth-3, XCD-swizzled grid ----------------
// 1D grid 512: xcd = bid&7; e = xcd*8 + (bid>>6); nc = (bid>>3)&7.
// All 8 nc-blocks of expert e share one XCD -> A-tile L2-resident after first read.

__global__ __launch_bounds__(256, 2) void ffn1_kernel(
    const unsigned short* __restrict__ xb, const float* __restrict__ W1,
    const int* __restrict__ offs, const int* __restrict__ perm,
    const float* __restrict__ wgt, unsigned short* __restrict__ hbuf)
{
  const int bid = blockIdx.x;
  const int e   = (bid & 7) * 8 + (bid >> 6);
  const int nc  = (bid >> 3) & 7;
  const int cnt = offs[e + 1] - offs[e];
  if (cnt == 0) return;

  __shared__ unsigned short Abuf[2][MT * 64];
  __shared__ unsigned short Bbuf[2][64 * 64];

  const int tid  = threadIdx.x;
  const int lane = tid & 63;
  const int wv   = tid >> 6;

  const int qB = tid & 15;
  const int rB = tid >> 4;
  const float* bptr[4];
  #pragma unroll
  for (int p = 0; p < 4; ++p)
    bptr[p] = W1 + ((long)e * D_HID + nc * 64 + p * 16 + rB) * D_MODEL + qB * 4;

  int arow[3], brow[4];
  int physA[2][3], physB[2][4];
  #pragma unroll
  for (int mi = 0; mi < 3; ++mi) {
    arow[mi] = wv * 48 + mi * 16 + (lane & 15);
    #pragma unroll
    for (int ks = 0; ks < 2; ++ks)
      physA[ks][mi] = (ks * 4 + (lane >> 4)) ^ (arow[mi] & 7);
  }
  #pragma unroll
  for (int ni = 0; ni < 4; ++ni) {
    brow[ni] = ni * 16 + (lane & 15);
    #pragma unroll
    for (int ks = 0; ks < 2; ++ks)
      physB[ks][ni] = (ks * 4 + (lane >> 4)) ^ (brow[ni] & 7);
  }
  const int lslot = (lane & 7) ^ (lane >> 3);

  for (int m0 = 0; m0 < cnt; m0 += MT) {
    const int base = offs[e] + m0;
    const int mcnt = min(MT, cnt - m0);

    const unsigned short* gptrA[6];
    #pragma unroll
    for (int j = 0; j < 6; ++j) {
      int pr = (wv * 6 + j) * 8 + (lane >> 3);
      if (pr >= mcnt) pr = mcnt - 1;
      gptrA[j] = xb + (long)perm[base + pr] * D_MODEL + lslot * 8;
    }

    f32x4 acc[3][4];
    #pragma unroll
    for (int i = 0; i < 3; ++i)
      #pragma unroll
      for (int j = 0; j < 4; ++j) acc[i][j] = (f32x4)0.f;

    float4 br0[4], br1[4], br2[4];

    auto ISSUEA = [&](int t, unsigned short* Ab) {
      const int k0 = t * 64;
      SCHED0;
      #pragma unroll
      for (int j = 0; j < 6; ++j)
        gl16(gptrA[j] + k0, Ab + (wv * 6 + j) * 512);
      SCHED0;
    };
    auto ISSUEB = [&](int t, float4* br) {
      const int k0 = t * 64;
      SCHED0;
      #pragma unroll
      for (int p = 0; p < 4; ++p) br[p] = *(const float4*)(bptr[p] + k0);
      SCHED0;
    };
    auto WRITE_B = [&](const float4* br, unsigned short* B_) {
      #pragma unroll
      for (int p = 0; p < 4; ++p) {
        int rr = p * 16 + rB;
        unsigned lo = pk2(br[p].x, br[p].y);
        unsigned hi = pk2(br[p].z, br[p].w);
        int ph = (qB >> 1) ^ (rr & 7);
        *(uint2*)(B_ + rr * 64 + ph * 8 + (qB & 1) * 4) = make_uint2(lo, hi);
      }
    };
    auto COMPUTE = [&](const unsigned short* A_, const unsigned short* B_) {
      #pragma unroll
      for (int ks = 0; ks < 2; ++ks) {
        short8 a[3], bb[4];
        #pragma unroll
        for (int mi = 0; mi < 3; ++mi)
          a[mi] = *(const short8*)(A_ + arow[mi] * 64 + physA[ks][mi] * 8);
        #pragma unroll
        for (int ni = 0; ni < 4; ++ni)
          bb[ni] = *(const short8*)(B_ + brow[ni] * 64 + physB[ks][ni] * 8);
        __builtin_amdgcn_s_setprio(1);
        #pragma unroll
        for (int mi = 0; mi < 3; ++mi)
          #pragma unroll
          for (int ni = 0; ni < 4; ++ni)
            acc[mi][ni] = __builtin_amdgcn_mfma_f32_16x16x32_bf16(a[mi], bb[ni], acc[mi][ni], 0, 0, 0);
        __builtin_amdgcn_s_setprio(0);
      }
    };

    ISSUEA(0, Abuf[0]); ISSUEB(0, br0);
    ISSUEA(1, Abuf[1]); ISSUEB(1, br1);
    ISSUEB(2, br2);
    WAITV(14);
    WRITE_B(br0, Bbuf[0]);
    WAITL0;
    SBAR;

    #pragma unroll 1
    for (int t = 0; t < NT1; t += 6) {
      FS(t + 0, 0, br0, br1, NT1);
      FS(t + 1, 1, br1, br2, NT1);
      FS(t + 2, 0, br2, br0, NT1);
      FS(t + 3, 1, br0, br1, NT1);
      FS(t + 4, 0, br1, br2, NT1);
      FS(t + 5, 1, br2, br0, NT1);
    }

    // epilogue: SiLU*gate -> bf16 via LDS transpose -> coalesced uint4 stores
    unsigned short* fds = &Abuf[0][0];
    const int rsub = (lane >> 4) * 4;
    const int csub = lane & 15;
    #pragma unroll
    for (int mi = 0; mi < 3; ++mi) {
      #pragma unroll
      for (int rg = 0; rg < 4; ++rg) {
        int r = wv * 48 + mi * 16 + rsub + rg;
        float wt = (r < mcnt) ? wgt[base + r] : 0.f;
        #pragma unroll
        for (int ni = 0; ni < 4; ++ni) {
          float v = acc[mi][ni][rg];
          float sv = v / (1.f + __expf(-v)) * wt;
          fds[r * 64 + ni * 16 + csub] = f2bf(sv);
        }
      }
    }
    __syncthreads();
    #pragma unroll
    for (int q = 0; q < 6; ++q) {
      int idx = q * 256 + tid;
      int row = idx >> 3, c8 = idx & 7;
      if (row < mcnt)
        *(uint4*)(hbuf + (long)(base + row) * D_HID + nc * 64 + c8 * 8) =
            *(const uint4*)(fds + row * 64 + c8 * 8);
    }
    __syncthreads();
  }
}

// ---------------- ffn2: same structure, XCD-swizzled grid, A = hbuf ----------------
// 1D grid 1536: xcd = bid&7; j = bid>>3 (0..191); e = xcd*8 + j/24; nc = j%24.

__global__ __launch_bounds__(256, 2) void ffn2_kernel(
    const unsigned short* __restrict__ hbuf, const float* __restrict__ W2,
    const int* __restrict__ offs, unsigned short* __restrict__ sbuf)
{
  const int bid = blockIdx.x;
  const int j   = bid >> 3;
  const int e   = (bid & 7) * 8 + j / 24;
  const int nc  = j % 24;
  const int cnt = offs[e + 1] - offs[e];
  if (cnt == 0) return;

  __shared__ unsigned short Abuf[2][MT * 64];
  __shared__ unsigned short Bbuf[2][64 * 64];

  const int tid  = threadIdx.x;
  const int lane = tid & 63;
  const int wv   = tid >> 6;

  const int qB = tid & 15;
  const int rB = tid >> 4;
  const float* bptr[4];
  #pragma unroll
  for (int p = 0; p < 4; ++p)
    bptr[p] = W2 + ((long)e * D_MODEL + nc * 64 + p * 16 + rB) * D_HID + qB * 4;

  int arow[3], brow[4];
  int physA[2][3], physB[2][4];
  #pragma unroll
  for (int mi = 0; mi < 3; ++mi) {
    arow[mi] = wv * 48 + mi * 16 + (lane & 15);
    #pragma unroll
    for (int ks = 0; ks < 2; ++ks)
      physA[ks][mi] = (ks * 4 + (lane >> 4)) ^ (arow[mi] & 7);
  }
  #pragma unroll
  for (int ni = 0; ni < 4; ++ni) {
    brow[ni] = ni * 16 + (lane & 15);
    #pragma unroll
    for (int ks = 0; ks < 2; ++ks)
      physB[ks][ni] = (ks * 4 + (lane >> 4)) ^ (brow[ni] & 7);
  }
  const int lslot = (lane & 7) ^ (lane >> 3);

  for (int m0 = 0; m0 < cnt; m0 += MT) {
    const int base = offs[e] + m0;
    const int mcnt = min(MT, cnt - m0);

    const unsigned short* gptrA[6];
    #pragma unroll
    for (int j2 = 0; j2 < 6; ++j2) {
      int pr = (wv * 6 + j2) * 8 + (lane >> 3);
      if (pr >= mcnt) pr = mcnt - 1;
      gptrA[j2] = hbuf + (long)(base + pr) * D_HID + lslot * 8;
    }

    f32x4 acc[3][4];
    #pragma unroll
    for (int i = 0; i < 3; ++i)
      #pragma unroll
      for (int j2 = 0; j2 < 4; ++j2) acc[i][j2] = (f32x4)0.f;

    float4 br0[4], br1[4], br2[4];

    auto ISSUEA = [&](int t, unsigned short* Ab) {
      const int k0 = t * 64;
      SCHED0;
      #pragma unroll
      for (int j2 = 0; j2 < 6; ++j2)
        gl16(gptrA[j2] + k0, Ab + (wv * 6 + j2) * 512);
      SCHED0;
    };
    auto ISSUEB = [&](int t, float4* br) {
      const int k0 = t * 64;
      SCHED0;
      #pragma unroll
      for (int p = 0; p < 4; ++p) br[p] = *(const float4*)(bptr[p] + k0);
      SCHED0;
    };
    auto WRITE_B = [&](const float4* br, unsigned short* B_) {
      #pragma unroll
      for (int p = 0; p < 4; ++p) {
        int rr = p * 16 + rB;
        unsigned lo = pk2(br[p].x, br[p].y);
        unsigned hi = pk2(br[p].z, br[p].w);
        int ph = (qB >> 1) ^ (rr & 7);
        *(uint2*)(B_ + rr * 64 + ph * 8 + (qB & 1) * 4) = make_uint2(lo, hi);
      }
    };
    auto COMPUTE = [&](const unsigned short* A_, const unsigned short* B_) {
      #pragma unroll
      for (int ks = 0; ks < 2; ++ks) {
        short8 a[3], bb[4];
        #pragma unroll
        for (int mi = 0; mi < 3; ++mi)
          a[mi] = *(const short8*)(A_ + arow[mi] * 64 + physA[ks][mi] * 8);
        #pragma unroll
        for (int ni = 0; ni < 4; ++ni)
          bb[ni] = *(const short8*)(B_ + brow[ni] * 64 + physB[ks][ni] * 8);
        __builtin_amdgcn_s_setprio(1);
        #pragma unroll
        for (int mi = 0; mi < 3; ++mi)
          #pragma unroll
          for (int ni = 0; ni < 4; ++ni)
            acc[mi][ni] = __builtin_amdgcn_mfma_f32_16x16x32_bf16(a[mi], bb[ni], acc[mi][ni], 0, 0, 0);
        __builtin_amdgcn_s_setprio(0);
      }
    };

    ISSUEA(0, Abuf[0]); ISSUEB(0, br0);
    ISSUEA(1, Abuf[1]); ISSUEB(1, br1);
    ISSUEB(2, br2);
    WAITV(14);
    WRITE_B(br0, Bbuf[0]);
    WAITL0;
    SBAR;

    // NT2 = 8, fully unrolled
    FS(0, 0, br0, br1, NT2);
    FS(1, 1, br1, br2, NT2);
    FS(2, 0, br2, br0, NT2);
    FS(3, 1, br0, br1, NT2);
    FS(4, 0, br1, br2, NT2);
    FS(5, 1, br2, br0, NT2);
    FS(6, 0, br0, br1, NT2);
    FS(7, 1, br1, br2, NT2);

    // epilogue: bf16 transpose via LDS -> coalesced uint4 stores
    unsigned short* fds = &Abuf[0][0];
    const int rsub = (lane >> 4) * 4;
    const int csub = lane & 15;
    #pragma unroll
    for (int mi = 0; mi < 3; ++mi) {
      #pragma unroll
      for (int rg = 0; rg < 4; ++rg) {
        int r = wv * 48 + mi * 16 + rsub + rg;
        #pragma unroll
        for (int ni = 0; ni < 4; ++ni)
          fds[r * 64 + ni * 16 + csub] = f2bf(acc[mi][ni][rg]);
      }
    }
    __syncthreads();
    #pragma unroll
    for (int q = 0; q < 6; ++q) {
      int idx = q * 256 + tid;
      int row = idx >> 3, c8 = idx & 7;
      if (row < mcnt)
        *(uint4*)(sbuf + (long)(base + row) * D_MODEL + nc * 64 + c8 * 8) =
            *(const uint4*)(fds + row * 64 + c8 * 8);
    }
    __syncthreads();
  }
}

// ---------------- gather + LayerNorm (bf16 sbuf) ----------------

__global__ __launch_bounds__(192) void ln_kernel(const unsigned short* __restrict__ sbuf,
    const int* __restrict__ tok2slot, float* __restrict__ out,
    const float* __restrict__ gamma, const float* __restrict__ beta)
{
  const int tid = threadIdx.x;
  const int t = blockIdx.x;
  const long r0 = (long)tok2slot[t * 2]     * D_MODEL;
  const long r1 = (long)tok2slot[t * 2 + 1] * D_MODEL;

  uint4 u0 = *(const uint4*)(sbuf + r0 + tid * 8);
  uint4 u1 = *(const uint4*)(sbuf + r1 + tid * 8);
  float v[8];
  {
    const unsigned* p0 = &u0.x;
    const unsigned* p1 = &u1.x;
    #pragma unroll
    for (int i = 0; i < 4; ++i) {
      v[i * 2]     = bf2f((unsigned short)(p0[i] & 0xFFFFu)) + bf2f((unsigned short)(p1[i] & 0xFFFFu));
      v[i * 2 + 1] = bf2f((unsigned short)(p0[i] >> 16))     + bf2f((unsigned short)(p1[i] >> 16));
    }
  }

  float s = 0.f, sq = 0.f;
  #pragma unroll
  for (int i = 0; i < 8; ++i) { s += v[i]; sq += v[i] * v[i]; }
  #pragma unroll
  for (int off = 32; off > 0; off >>= 1) {
    s  += __shfl_xor(s, off);
    sq += __shfl_xor(sq, off);
  }
  __shared__ float ss[3], sqs[3];
  int wv = tid >> 6;
  if ((tid & 63) == 0) { ss[wv] = s; sqs[wv] = sq; }
  __syncthreads();
  s  = ss[0] + ss[1] + ss[2];
  sq = sqs[0] + sqs[1] + sqs[2];
  const float inv = 1.f / (float)D_MODEL;
  float mu  = s * inv;
  float var = sq * inv - mu * mu;
  float rs  = 1.f / sqrtf(var + 1e-5f);

  float4 g1 = *(const float4*)(gamma + tid * 8);
  float4 g2 = *(const float4*)(gamma + tid * 8 + 4);
  float4 b1v = *(const float4*)(beta + tid * 8);
  float4 b2v = *(const float4*)(beta + tid * 8 + 4);
  float4 a, b;
  a.x = (v[0] - mu) * rs * g1.x + b1v.x;
  a.y = (v[1] - mu) * rs * g1.y + b1v.y;
  a.z = (v[2] - mu) * rs * g1.z + b1v.z;
  a.w = (v[3] - mu) * rs * g1.w + b1v.w;
  b.x = (v[4] - mu) * rs * g2.x + b2v.x;
  b.y = (v[5] - mu) * rs * g2.y + b2v.y;
  b.z = (v[6] - mu) * rs * g2.z + b2v.z;
  b.w = (v[7] - mu) * rs * g2.w + b2v.w;
  float* row = out + (long)t * D_MODEL;
  *(float4*)(row + tid * 8)     = a;
  *(float4*)(row + tid * 8 + 4) = b;
}

// ---------------- launch ----------------

extern "C" void kernel_launch(void* const* d_in, const int* in_sizes, int n_in,
                              void* d_out, int out_size, void* d_ws, size_t ws_size,
                              hipStream_t stream) {
  const float* x     = (const float*)d_in[0];
  const float* Wr    = (const float*)d_in[1];
  const float* W1    = (const float*)d_in[2];
  const float* W2    = (const float*)d_in[3];
  const float* gamma = (const float*)d_in[4];
  const float* beta  = (const float*)d_in[5];
  float* out = (float*)d_out;

  char* ws = (char*)d_ws;
  unsigned short* xhi    = (unsigned short*)(ws + 0);          // 12,582,912
  unsigned short* xlo    = (unsigned short*)(ws + 12582912);   // 12,582,912
  unsigned short* hbuf   = (unsigned short*)(ws + 25165824);   //  8,388,608
  unsigned short* sbuf   = (unsigned short*)(ws + 33554432);   // 25,165,824
  unsigned short* whi    = (unsigned short*)(ws + 58720256);   //    196,608
  unsigned short* wlo    = (unsigned short*)(ws + 58916864);   //    196,608
  int*   topidx   = (int*)  (ws + 59113472);                   //     32,768
  float* topw     = (float*)(ws + 59146240);                   //     32,768
  int*   counts   = (int*)  (ws + 59179008);                   //        256
  int*   cursor   = (int*)  (ws + 59179264);                   //        256
  int*   offs     = (int*)  (ws + 59179520);                   //        512
  int*   tok2slot = (int*)  (ws + 59180032);                   //     32,768
  int*   perm     = (int*)  (ws + 59212800);                   //     32,768
  float* wgt      = (float*)(ws + 59245568);                   //     32,768

  hipLaunchKernelGGL(zero_small_kernel, dim3(1), dim3(64), 0, stream, counts);
  hipLaunchKernelGGL(cvt_split_kernel, dim3(3120), dim3(256), 0, stream, x, Wr, xhi, xlo, whi, wlo);
  hipLaunchKernelGGL(router_kernel, dim3(NTOK / 64), dim3(256), 0, stream, xhi, xlo, whi, wlo, topidx, topw, counts);
  hipLaunchKernelGGL(scan_kernel, dim3(1), dim3(64), 0, stream, counts, offs, cursor);
  hipLaunchKernelGGL(scatter_kernel, dim3(NTOK / 256), dim3(256), 0, stream, topidx, topw, offs, cursor, perm, wgt, tok2slot);
  hipLaunchKernelGGL(ffn1_kernel, dim3(512), dim3(256), 0, stream, xhi, W1, offs, perm, wgt, hbuf);
  hipLaunchKernelGGL(ffn2_kernel, dim3(1536), dim3(256), 0, stream, hbuf, W2, offs, sbuf);
  hipLaunchKernelGGL(ln_kernel, dim3(NTOK), dim3(192), 0, stream, sbuf, tok2slot, out, gamma, beta);
}

// Round 19
// 215.237 us; speedup vs baseline: 1.0364x; 1.0364x over previous
//
#include <hip/hip_runtime.h>
#include <hip/hip_bf16.h>

#define D_MODEL 1536
#define NEXP    64
#define D_HID   512
#define NTOK    4096
#define NT1     (D_MODEL / 64)   // 24 K-steps
#define NT2     (D_HID / 64)     // 8 K-steps
#define MT      192              // packed M rows per block pass

typedef __attribute__((ext_vector_type(8))) short short8;
typedef __attribute__((ext_vector_type(4))) float f32x4;

__device__ __forceinline__ unsigned short f2bf(float f) {
  unsigned u = __builtin_bit_cast(unsigned, f);
  u += 0x7FFFu + ((u >> 16) & 1u);
  return (unsigned short)(u >> 16);
}
__device__ __forceinline__ unsigned pk2(float a, float b) {
  return (unsigned)f2bf(a) | ((unsigned)f2bf(b) << 16);
}
__device__ __forceinline__ float bf2f(unsigned short u) {
  return __builtin_bit_cast(float, ((unsigned)u) << 16);
}

__device__ __forceinline__ void gl16(const void* g, void* s) {
  __builtin_amdgcn_global_load_lds(
      (const __attribute__((address_space(1))) unsigned int*)g,
      (__attribute__((address_space(3))) unsigned int*)s, 16, 0, 0);
}

#define WAITV(N)  asm volatile("s_waitcnt vmcnt(" #N ")" ::: "memory")
#define WAITL0    asm volatile("s_waitcnt lgkmcnt(0)" ::: "memory")
#define SBAR      __builtin_amdgcn_s_barrier()
#define SCHED0    __builtin_amdgcn_sched_barrier(0)

// ---------------- utility ----------------

__global__ void zero_small_kernel(int* __restrict__ counts) {
  counts[threadIdx.x] = 0;
}

// ---------------- split conversion: x -> (xhi, xlo), Wr -> (whi, wlo) ----------------

__global__ __launch_bounds__(256) void cvt_split_kernel(const float* __restrict__ x,
    const float* __restrict__ Wr,
    unsigned short* __restrict__ xhi, unsigned short* __restrict__ xlo,
    unsigned short* __restrict__ whi, unsigned short* __restrict__ wlo)
{
  const float* src; unsigned short* dhi; unsigned short* dlo; long i;
  long bid = blockIdx.x;
  if (bid < 3072) { src = x;  dhi = xhi; dlo = xlo; i = (bid * 256 + threadIdx.x) * 8; }
  else            { src = Wr; dhi = whi; dlo = wlo; i = ((bid - 3072) * 256 + threadIdx.x) * 8; }
  float4 a = *(const float4*)(src + i);
  float4 b = *(const float4*)(src + i + 4);
  float f[8] = {a.x, a.y, a.z, a.w, b.x, b.y, b.z, b.w};
  unsigned short h[8], l[8];
  #pragma unroll
  for (int j = 0; j < 8; ++j) {
    h[j] = f2bf(f[j]);
    l[j] = f2bf(f[j] - bf2f(h[j]));
  }
  uint4 ph, pl;
  ph.x = (unsigned)h[0] | ((unsigned)h[1] << 16);
  ph.y = (unsigned)h[2] | ((unsigned)h[3] << 16);
  ph.z = (unsigned)h[4] | ((unsigned)h[5] << 16);
  ph.w = (unsigned)h[6] | ((unsigned)h[7] << 16);
  pl.x = (unsigned)l[0] | ((unsigned)l[1] << 16);
  pl.y = (unsigned)l[2] | ((unsigned)l[3] << 16);
  pl.z = (unsigned)l[4] | ((unsigned)l[5] << 16);
  pl.w = (unsigned)l[6] | ((unsigned)l[7] << 16);
  *(uint4*)(dhi + i) = ph;
  *(uint4*)(dlo + i) = pl;
}

// ---------------- router v5: split-bf16 MFMA GEMM + in-kernel top-2 ----------------

__global__ __launch_bounds__(256) void router_kernel(
    const unsigned short* __restrict__ xhi, const unsigned short* __restrict__ xlo,
    const unsigned short* __restrict__ whi, const unsigned short* __restrict__ wlo,
    int* __restrict__ topidx, float* __restrict__ topw, int* __restrict__ counts)
{
  __shared__ unsigned short lds[8 * 4096];
  const int tid  = threadIdx.x;
  const int lane = tid & 63;
  const int wv   = tid >> 6;
  const int t0   = blockIdx.x * 64;

  const int lslot = (lane & 7) ^ (lane >> 3);
  const unsigned short* gsrc[4][2];
  #pragma unroll
  for (int j = 0; j < 2; ++j) {
    int r = (wv * 2 + j) * 8 + (lane >> 3);
    gsrc[0][j] = xhi + (long)(t0 + r) * D_MODEL + lslot * 8;
    gsrc[1][j] = xlo + (long)(t0 + r) * D_MODEL + lslot * 8;
    gsrc[2][j] = whi + (long)r * D_MODEL + lslot * 8;
    gsrc[3][j] = wlo + (long)r * D_MODEL + lslot * 8;
  }

  auto ISSUE = [&](int t, int b) {
    const int k0 = t * 64;
    SCHED0;
    #pragma unroll
    for (int tile = 0; tile < 4; ++tile)
      #pragma unroll
      for (int j = 0; j < 2; ++j)
        gl16(gsrc[tile][j] + k0, &lds[(b * 4 + tile) * 4096 + (wv * 2 + j) * 512]);
    SCHED0;
  };

  f32x4 acc[4];
  #pragma unroll
  for (int i = 0; i < 4; ++i) acc[i] = (f32x4)0.f;

  const int arow = wv * 16 + (lane & 15);

  auto COMPUTE = [&](int b) {
    const unsigned short* Ah = &lds[(b * 4 + 0) * 4096];
    const unsigned short* Al = &lds[(b * 4 + 1) * 4096];
    const unsigned short* Bh = &lds[(b * 4 + 2) * 4096];
    const unsigned short* Bl = &lds[(b * 4 + 3) * 4096];
    #pragma unroll
    for (int ks = 0; ks < 2; ++ks) {
      int pa = (ks * 4 + (lane >> 4)) ^ (arow & 7);
      short8 ah = *(const short8*)(Ah + arow * 64 + pa * 8);
      short8 al = *(const short8*)(Al + arow * 64 + pa * 8);
      short8 bh[4], bl[4];
      #pragma unroll
      for (int ni = 0; ni < 4; ++ni) {
        int br = ni * 16 + (lane & 15);
        int pb = (ks * 4 + (lane >> 4)) ^ (br & 7);
        bh[ni] = *(const short8*)(Bh + br * 64 + pb * 8);
        bl[ni] = *(const short8*)(Bl + br * 64 + pb * 8);
      }
      __builtin_amdgcn_s_setprio(1);
      #pragma unroll
      for (int ni = 0; ni < 4; ++ni) {
        acc[ni] = __builtin_amdgcn_mfma_f32_16x16x32_bf16(ah, bh[ni], acc[ni], 0, 0, 0);
        acc[ni] = __builtin_amdgcn_mfma_f32_16x16x32_bf16(ah, bl[ni], acc[ni], 0, 0, 0);
        acc[ni] = __builtin_amdgcn_mfma_f32_16x16x32_bf16(al, bh[ni], acc[ni], 0, 0, 0);
      }
      __builtin_amdgcn_s_setprio(0);
    }
  };

  ISSUE(0, 0);
  ISSUE(1, 1);
  WAITV(8);
  SBAR;

  #pragma unroll 1
  for (int t = 0; t < NT1; t += 2) {
    COMPUTE(0);
    SBAR;
    if (t + 2 < NT1) { ISSUE(t + 2, 0); WAITV(8); }
    else             { WAITV(0); }
    SBAR;
    COMPUTE(1);
    SBAR;
    if (t + 2 < NT1) {
      if (t + 3 < NT1) { ISSUE(t + 3, 1); WAITV(8); }
      else             { WAITV(0); }
      SBAR;
    }
  }

  float* lgl = (float*)lds;           // [64][66]
  #pragma unroll
  for (int ni = 0; ni < 4; ++ni)
    #pragma unroll
    for (int rg = 0; rg < 4; ++rg) {
      int tok = wv * 16 + (lane >> 4) * 4 + rg;
      int e   = ni * 16 + (lane & 15);
      lgl[tok * 66 + e] = acc[ni][rg];
    }
  __syncthreads();

  for (int i = 0; i < 16; ++i) {
    const int tl = wv * 16 + i;
    float v = lgl[tl * 66 + lane];
    float v0 = v; int e0 = lane;
    #pragma unroll
    for (int off = 32; off > 0; off >>= 1) {
      float ov = __shfl_xor(v0, off);
      int   oe = __shfl_xor(e0, off);
      if (ov > v0 || (ov == v0 && oe < e0)) { v0 = ov; e0 = oe; }
    }
    float v1 = (lane == e0) ? -3.0e38f : v;
    int e1 = lane;
    #pragma unroll
    for (int off = 32; off > 0; off >>= 1) {
      float ov = __shfl_xor(v1, off);
      int   oe = __shfl_xor(e1, off);
      if (ov > v1 || (ov == v1 && oe < e1)) { v1 = ov; e1 = oe; }
    }
    if (lane == 0) {
      int tt = t0 + tl;
      float w0 = 1.f / (1.f + expf(v1 - v0));
      topidx[tt * 2]     = e0;
      topidx[tt * 2 + 1] = e1;
      topw[tt * 2]       = w0;
      topw[tt * 2 + 1]   = 1.f - w0;
      atomicAdd(&counts[e0], 1);
      atomicAdd(&counts[e1], 1);
    }
  }
}

// ---------------- scan + scatter ----------------

__global__ void scan_kernel(const int* __restrict__ counts, int* __restrict__ offs,
                            int* __restrict__ cursor)
{
  int e = threadIdx.x;
  int c = counts[e];
  int xx = c;
  #pragma unroll
  for (int off = 1; off < 64; off <<= 1) {
    int y = __shfl_up(xx, off);
    if (e >= off) xx += y;
  }
  offs[e + 1] = xx;
  if (e == 0) offs[0] = 0;
  cursor[e] = 0;
}

__global__ void scatter_kernel(const int* __restrict__ topidx, const float* __restrict__ topw,
    const int* __restrict__ offs, int* __restrict__ cursor,
    int* __restrict__ perm, float* __restrict__ wgt, int* __restrict__ tok2slot)
{
  int t = blockIdx.x * blockDim.x + threadIdx.x;
  if (t >= NTOK) return;
  #pragma unroll
  for (int k = 0; k < 2; ++k) {
    int e = topidx[t * 2 + k];
    float w = topw[t * 2 + k];
    int pos = atomicAdd(&cursor[e], 1);
    int slot = offs[e] + pos;
    perm[slot] = t;
    wgt[slot] = w;
    tok2slot[t * 2 + k] = slot;
  }
}

// ---- pipelined step, de-walled: B-write overlapped with ks1 compute ----
// steady in-flight entering FS(T): B(T+1),A(T+1),B(T+2) (14). mid-wait
// guarantees B(T+1) regs (newer = A(T+1)+B(T+2) = 10; tail 6); end-wait
// guarantees A(T+1) (newer = B(T+2)+A(T+2)+B(T+3) = 14 / 10 / 0).
#define FS(T, AB, BRI, BRW, KNT)                                    \
  {                                                                 \
    CKS(Abuf[AB], Bbuf[AB], 0);                                     \
    if ((T) + 1 < (KNT)) {                                          \
      if ((T) + 2 < (KNT)) { WAITV(10); } else { WAITV(6); }        \
      WRITE_B(BRW, Bbuf[(AB) ^ 1]);                                 \
    }                                                               \
    CKS(Abuf[AB], Bbuf[AB], 1);                                     \
    SBAR;                                                           \
    if ((T) + 2 < (KNT)) ISSUEA((T) + 2, Abuf[AB]);                 \
    if ((T) + 3 < (KNT)) ISSUEB((T) + 3, BRI);                      \
    if ((T) + 3 < (KNT))      { WAITV(14); }                        \
    else if ((T) + 2 < (KNT)) { WAITV(10); }                        \
    else                      { WAITV(0);  }                        \
    WAITL0;                                                         \
    SBAR;                                                           \
  }

// ---------------- ffn1: 256-thread, B depth-3, XCD-swizzled grid ----------------

__global__ __launch_bounds__(256, 2) void ffn1_kernel(
    const unsigned short* __restrict__ xb, const float* __restrict__ W1,
    const int* __restrict__ offs, const int* __restrict__ perm,
    const float* __restrict__ wgt, unsigned short* __restrict__ hbuf)
{
  const int bid = blockIdx.x;
  const int e   = (bid & 7) * 8 + (bid >> 6);
  const int nc  = (bid >> 3) & 7;
  const int cnt = offs[e + 1] - offs[e];
  if (cnt == 0) return;

  __shared__ unsigned short Abuf[2][MT * 64];
  __shared__ unsigned short Bbuf[2][64 * 64];

  const int tid  = threadIdx.x;
  const int lane = tid & 63;
  const int wv   = tid >> 6;

  const int qB = tid & 15;
  const int rB = tid >> 4;
  const float* bptr[4];
  #pragma unroll
  for (int p = 0; p < 4; ++p)
    bptr[p] = W1 + ((long)e * D_HID + nc * 64 + p * 16 + rB) * D_MODEL + qB * 4;

  int arow[3], brow[4];
  int physA[2][3], physB[2][4];
  #pragma unroll
  for (int mi = 0; mi < 3; ++mi) {
    arow[mi] = wv * 48 + mi * 16 + (lane & 15);
    #pragma unroll
    for (int ks = 0; ks < 2; ++ks)
      physA[ks][mi] = (ks * 4 + (lane >> 4)) ^ (arow[mi] & 7);
  }
  #pragma unroll
  for (int ni = 0; ni < 4; ++ni) {
    brow[ni] = ni * 16 + (lane & 15);
    #pragma unroll
    for (int ks = 0; ks < 2; ++ks)
      physB[ks][ni] = (ks * 4 + (lane >> 4)) ^ (brow[ni] & 7);
  }
  const int lslot = (lane & 7) ^ (lane >> 3);

  for (int m0 = 0; m0 < cnt; m0 += MT) {
    const int base = offs[e] + m0;
    const int mcnt = min(MT, cnt - m0);

    const unsigned short* gptrA[6];
    #pragma unroll
    for (int j = 0; j < 6; ++j) {
      int pr = (wv * 6 + j) * 8 + (lane >> 3);
      if (pr >= mcnt) pr = mcnt - 1;
      gptrA[j] = xb + (long)perm[base + pr] * D_MODEL + lslot * 8;
    }

    f32x4 acc[3][4];
    #pragma unroll
    for (int i = 0; i < 3; ++i)
      #pragma unroll
      for (int j = 0; j < 4; ++j) acc[i][j] = (f32x4)0.f;

    float4 br0[4], br1[4], br2[4];

    auto ISSUEA = [&](int t, unsigned short* Ab) {
      const int k0 = t * 64;
      #pragma unroll
      for (int j = 0; j < 6; ++j)
        gl16(gptrA[j] + k0, Ab + (wv * 6 + j) * 512);
    };
    auto ISSUEB = [&](int t, float4* br) {
      const int k0 = t * 64;
      #pragma unroll
      for (int p = 0; p < 4; ++p) br[p] = *(const float4*)(bptr[p] + k0);
    };
    auto WRITE_B = [&](const float4* br, unsigned short* B_) {
      #pragma unroll
      for (int p = 0; p < 4; ++p) {
        int rr = p * 16 + rB;
        unsigned lo = pk2(br[p].x, br[p].y);
        unsigned hi = pk2(br[p].z, br[p].w);
        int ph = (qB >> 1) ^ (rr & 7);
        *(uint2*)(B_ + rr * 64 + ph * 8 + (qB & 1) * 4) = make_uint2(lo, hi);
      }
    };
    auto CKS = [&](const unsigned short* A_, const unsigned short* B_, int ks) {
      short8 a[3], bb[4];
      #pragma unroll
      for (int mi = 0; mi < 3; ++mi)
        a[mi] = *(const short8*)(A_ + arow[mi] * 64 + physA[ks][mi] * 8);
      #pragma unroll
      for (int ni = 0; ni < 4; ++ni)
        bb[ni] = *(const short8*)(B_ + brow[ni] * 64 + physB[ks][ni] * 8);
      #pragma unroll
      for (int mi = 0; mi < 3; ++mi)
        #pragma unroll
        for (int ni = 0; ni < 4; ++ni)
          acc[mi][ni] = __builtin_amdgcn_mfma_f32_16x16x32_bf16(a[mi], bb[ni], acc[mi][ni], 0, 0, 0);
    };

    // prologue (FIFO order matches steady state: ...B1, A1, B2 newest)
    ISSUEA(0, Abuf[0]); ISSUEB(0, br0);
    ISSUEB(1, br1);
    ISSUEA(1, Abuf[1]); ISSUEB(2, br2);
    WAITV(14);                       // newest 14 = B1,A1,B2 -> A0,B0 landed
    WRITE_B(br0, Bbuf[0]);
    WAITL0;
    SBAR;

    #pragma unroll 1
    for (int t = 0; t < NT1; t += 6) {
      FS(t + 0, 0, br0, br1, NT1);
      FS(t + 1, 1, br1, br2, NT1);
      FS(t + 2, 0, br2, br0, NT1);
      FS(t + 3, 1, br0, br1, NT1);
      FS(t + 4, 0, br1, br2, NT1);
      FS(t + 5, 1, br2, br0, NT1);
    }

    // epilogue: SiLU*gate -> bf16 via LDS transpose -> coalesced uint4 stores
    unsigned short* fds = &Abuf[0][0];
    const int rsub = (lane >> 4) * 4;
    const int csub = lane & 15;
    #pragma unroll
    for (int mi = 0; mi < 3; ++mi) {
      #pragma unroll
      for (int rg = 0; rg < 4; ++rg) {
        int r = wv * 48 + mi * 16 + rsub + rg;
        float wt = (r < mcnt) ? wgt[base + r] : 0.f;
        #pragma unroll
        for (int ni = 0; ni < 4; ++ni) {
          float v = acc[mi][ni][rg];
          float sv = v / (1.f + __expf(-v)) * wt;
          fds[r * 64 + ni * 16 + csub] = f2bf(sv);
        }
      }
    }
    __syncthreads();
    #pragma unroll
    for (int q = 0; q < 6; ++q) {
      int idx = q * 256 + tid;
      int row = idx >> 3, c8 = idx & 7;
      if (row < mcnt)
        *(uint4*)(hbuf + (long)(base + row) * D_HID + nc * 64 + c8 * 8) =
            *(const uint4*)(fds + row * 64 + c8 * 8);
    }
    __syncthreads();
  }
}

// ---------------- ffn2: same structure, XCD-swizzled grid, A = hbuf ----------------

__global__ __launch_bounds__(256, 2) void ffn2_kernel(
    const unsigned short* __restrict__ hbuf, const float* __restrict__ W2,
    const int* __restrict__ offs, unsigned short* __restrict__ sbuf)
{
  const int bid = blockIdx.x;
  const int j   = bid >> 3;
  const int e   = (bid & 7) * 8 + j / 24;
  const int nc  = j % 24;
  const int cnt = offs[e + 1] - offs[e];
  if (cnt == 0) return;

  __shared__ unsigned short Abuf[2][MT * 64];
  __shared__ unsigned short Bbuf[2][64 * 64];

  const int tid  = threadIdx.x;
  const int lane = tid & 63;
  const int wv   = tid >> 6;

  const int qB = tid & 15;
  const int rB = tid >> 4;
  const float* bptr[4];
  #pragma unroll
  for (int p = 0; p < 4; ++p)
    bptr[p] = W2 + ((long)e * D_MODEL + nc * 64 + p * 16 + rB) * D_HID + qB * 4;

  int arow[3], brow[4];
  int physA[2][3], physB[2][4];
  #pragma unroll
  for (int mi = 0; mi < 3; ++mi) {
    arow[mi] = wv * 48 + mi * 16 + (lane & 15);
    #pragma unroll
    for (int ks = 0; ks < 2; ++ks)
      physA[ks][mi] = (ks * 4 + (lane >> 4)) ^ (arow[mi] & 7);
  }
  #pragma unroll
  for (int ni = 0; ni < 4; ++ni) {
    brow[ni] = ni * 16 + (lane & 15);
    #pragma unroll
    for (int ks = 0; ks < 2; ++ks)
      physB[ks][ni] = (ks * 4 + (lane >> 4)) ^ (brow[ni] & 7);
  }
  const int lslot = (lane & 7) ^ (lane >> 3);

  for (int m0 = 0; m0 < cnt; m0 += MT) {
    const int base = offs[e] + m0;
    const int mcnt = min(MT, cnt - m0);

    const unsigned short* gptrA[6];
    #pragma unroll
    for (int j2 = 0; j2 < 6; ++j2) {
      int pr = (wv * 6 + j2) * 8 + (lane >> 3);
      if (pr >= mcnt) pr = mcnt - 1;
      gptrA[j2] = hbuf + (long)(base + pr) * D_HID + lslot * 8;
    }

    f32x4 acc[3][4];
    #pragma unroll
    for (int i = 0; i < 3; ++i)
      #pragma unroll
      for (int j2 = 0; j2 < 4; ++j2) acc[i][j2] = (f32x4)0.f;

    float4 br0[4], br1[4], br2[4];

    auto ISSUEA = [&](int t, unsigned short* Ab) {
      const int k0 = t * 64;
      #pragma unroll
      for (int j2 = 0; j2 < 6; ++j2)
        gl16(gptrA[j2] + k0, Ab + (wv * 6 + j2) * 512);
    };
    auto ISSUEB = [&](int t, float4* br) {
      const int k0 = t * 64;
      #pragma unroll
      for (int p = 0; p < 4; ++p) br[p] = *(const float4*)(bptr[p] + k0);
    };
    auto WRITE_B = [&](const float4* br, unsigned short* B_) {
      #pragma unroll
      for (int p = 0; p < 4; ++p) {
        int rr = p * 16 + rB;
        unsigned lo = pk2(br[p].x, br[p].y);
        unsigned hi = pk2(br[p].z, br[p].w);
        int ph = (qB >> 1) ^ (rr & 7);
        *(uint2*)(B_ + rr * 64 + ph * 8 + (qB & 1) * 4) = make_uint2(lo, hi);
      }
    };
    auto CKS = [&](const unsigned short* A_, const unsigned short* B_, int ks) {
      short8 a[3], bb[4];
      #pragma unroll
      for (int mi = 0; mi < 3; ++mi)
        a[mi] = *(const short8*)(A_ + arow[mi] * 64 + physA[ks][mi] * 8);
      #pragma unroll
      for (int ni = 0; ni < 4; ++ni)
        bb[ni] = *(const short8*)(B_ + brow[ni] * 64 + physB[ks][ni] * 8);
      #pragma unroll
      for (int mi = 0; mi < 3; ++mi)
        #pragma unroll
        for (int ni = 0; ni < 4; ++ni)
          acc[mi][ni] = __builtin_amdgcn_mfma_f32_16x16x32_bf16(a[mi], bb[ni], acc[mi][ni], 0, 0, 0);
    };

    ISSUEA(0, Abuf[0]); ISSUEB(0, br0);
    ISSUEB(1, br1);
    ISSUEA(1, Abuf[1]); ISSUEB(2, br2);
    WAITV(14);
    WRITE_B(br0, Bbuf[0]);
    WAITL0;
    SBAR;

    // NT2 = 8, fully unrolled
    FS(0, 0, br0, br1, NT2);
    FS(1, 1, br1, br2, NT2);
    FS(2, 0, br2, br0, NT2);
    FS(3, 1, br0, br1, NT2);
    FS(4, 0, br1, br2, NT2);
    FS(5, 1, br2, br0, NT2);
    FS(6, 0, br0, br1, NT2);
    FS(7, 1, br1, br2, NT2);

    // epilogue: bf16 transpose via LDS -> coalesced uint4 stores
    unsigned short* fds = &Abuf[0][0];
    const int rsub = (lane >> 4) * 4;
    const int csub = lane & 15;
    #pragma unroll
    for (int mi = 0; mi < 3; ++mi) {
      #pragma unroll
      for (int rg = 0; rg < 4; ++rg) {
        int r = wv * 48 + mi * 16 + rsub + rg;
        #pragma unroll
        for (int ni = 0; ni < 4; ++ni)
          fds[r * 64 + ni * 16 + csub] = f2bf(acc[mi][ni][rg]);
      }
    }
    __syncthreads();
    #pragma unroll
    for (int q = 0; q < 6; ++q) {
      int idx = q * 256 + tid;
      int row = idx >> 3, c8 = idx & 7;
      if (row < mcnt)
        *(uint4*)(sbuf + (long)(base + row) * D_MODEL + nc * 64 + c8 * 8) =
            *(const uint4*)(fds + row * 64 + c8 * 8);
    }
    __syncthreads();
  }
}

// ---------------- gather + LayerNorm (bf16 sbuf) ----------------

__global__ __launch_bounds__(192) void ln_kernel(const unsigned short* __restrict__ sbuf,
    const int* __restrict__ tok2slot, float* __restrict__ out,
    const float* __restrict__ gamma, const float* __restrict__ beta)
{
  const int tid = threadIdx.x;
  const int t = blockIdx.x;
  const long r0 = (long)tok2slot[t * 2]     * D_MODEL;
  const long r1 = (long)tok2slot[t * 2 + 1] * D_MODEL;

  uint4 u0 = *(const uint4*)(sbuf + r0 + tid * 8);
  uint4 u1 = *(const uint4*)(sbuf + r1 + tid * 8);
  float v[8];
  {
    const unsigned* p0 = &u0.x;
    const unsigned* p1 = &u1.x;
    #pragma unroll
    for (int i = 0; i < 4; ++i) {
      v[i * 2]     = bf2f((unsigned short)(p0[i] & 0xFFFFu)) + bf2f((unsigned short)(p1[i] & 0xFFFFu));
      v[i * 2 + 1] = bf2f((unsigned short)(p0[i] >> 16))     + bf2f((unsigned short)(p1[i] >> 16));
    }
  }

  float s = 0.f, sq = 0.f;
  #pragma unroll
  for (int i = 0; i < 8; ++i) { s += v[i]; sq += v[i] * v[i]; }
  #pragma unroll
  for (int off = 32; off > 0; off >>= 1) {
    s  += __shfl_xor(s, off);
    sq += __shfl_xor(sq, off);
  }
  __shared__ float ss[3], sqs[3];
  int wv = tid >> 6;
  if ((tid & 63) == 0) { ss[wv] = s; sqs[wv] = sq; }
  __syncthreads();
  s  = ss[0] + ss[1] + ss[2];
  sq = sqs[0] + sqs[1] + sqs[2];
  const float inv = 1.f / (float)D_MODEL;
  float mu  = s * inv;
  float var = sq * inv - mu * mu;
  float rs  = 1.f / sqrtf(var + 1e-5f);

  float4 g1 = *(const float4*)(gamma + tid * 8);
  float4 g2 = *(const float4*)(gamma + tid * 8 + 4);
  float4 b1v = *(const float4*)(beta + tid * 8);
  float4 b2v = *(const float4*)(beta + tid * 8 + 4);
  float4 a, b;
  a.x = (v[0] - mu) * rs * g1.x + b1v.x;
  a.y = (v[1] - mu) * rs * g1.y + b1v.y;
  a.z = (v[2] - mu) * rs * g1.z + b1v.z;
  a.w = (v[3] - mu) * rs * g1.w + b1v.w;
  b.x = (v[4] - mu) * rs * g2.x + b2v.x;
  b.y = (v[5] - mu) * rs * g2.y + b2v.y;
  b.z = (v[6] - mu) * rs * g2.z + b2v.z;
  b.w = (v[7] - mu) * rs * g2.w + b2v.w;
  float* row = out + (long)t * D_MODEL;
  *(float4*)(row + tid * 8)     = a;
  *(float4*)(row + tid * 8 + 4) = b;
}

// ---------------- launch ----------------

extern "C" void kernel_launch(void* const* d_in, const int* in_sizes, int n_in,
                              void* d_out, int out_size, void* d_ws, size_t ws_size,
                              hipStream_t stream) {
  const float* x     = (const float*)d_in[0];
  const float* Wr    = (const float*)d_in[1];
  const float* W1    = (const float*)d_in[2];
  const float* W2    = (const float*)d_in[3];
  const float* gamma = (const float*)d_in[4];
  const float* beta  = (const float*)d_in[5];
  float* out = (float*)d_out;

  char* ws = (char*)d_ws;
  unsigned short* xhi    = (unsigned short*)(ws + 0);          // 12,582,912
  unsigned short* xlo    = (unsigned short*)(ws + 12582912);   // 12,582,912
  unsigned short* hbuf   = (unsigned short*)(ws + 25165824);   //  8,388,608
  unsigned short* sbuf   = (unsigned short*)(ws + 33554432);   // 25,165,824
  unsigned short* whi    = (unsigned short*)(ws + 58720256);   //    196,608
  unsigned short* wlo    = (unsigned short*)(ws + 58916864);   //    196,608
  int*   topidx   = (int*)  (ws + 59113472);                   //     32,768
  float* topw     = (float*)(ws + 59146240);                   //     32,768
  int*   counts   = (int*)  (ws + 59179008);                   //        256
  int*   cursor   = (int*)  (ws + 59179264);                   //        256
  int*   offs     = (int*)  (ws + 59179520);                   //        512
  int*   tok2slot = (int*)  (ws + 59180032);                   //     32,768
  int*   perm     = (int*)  (ws + 59212800);                   //     32,768
  float* wgt      = (float*)(ws + 59245568);                   //     32,768

  hipLaunchKernelGGL(zero_small_kernel, dim3(1), dim3(64), 0, stream, counts);
  hipLaunchKernelGGL(cvt_split_kernel, dim3(3120), dim3(256), 0, stream, x, Wr, xhi, xlo, whi, wlo);
  hipLaunchKernelGGL(router_kernel, dim3(NTOK / 64), dim3(256), 0, stream, xhi, xlo, whi, wlo, topidx, topw, counts);
  hipLaunchKernelGGL(scan_kernel, dim3(1), dim3(64), 0, stream, counts, offs, cursor);
  hipLaunchKernelGGL(scatter_kernel, dim3(NTOK / 256), dim3(256), 0, stream, topidx, topw, offs, cursor, perm, wgt, tok2slot);
  hipLaunchKernelGGL(ffn1_kernel, dim3(512), dim3(256), 0, stream, xhi, W1, offs, perm, wgt, hbuf);
  hipLaunchKernelGGL(ffn2_kernel, dim3(1536), dim3(256), 0, stream, hbuf, W2, offs, sbuf);
  hipLaunchKernelGGL(ln_kernel, dim3(NTOK), dim3(192), 0, stream, sbuf, tok2slot, out, gamma, beta);
}

// Round 20
// 208.448 us; speedup vs baseline: 1.0702x; 1.0326x over previous
//
#include <hip/hip_runtime.h>
#include <hip/hip_bf16.h>

#define D_MODEL 1536
#define NEXP    64
#define D_HID   512
#define NTOK    4096
#define NT1     (D_MODEL / 64)   // 24 K-steps
#define NT2     (D_HID / 64)     // 8 K-steps
#define MT      192              // packed M rows per block pass

typedef __attribute__((ext_vector_type(8))) short short8;
typedef __attribute__((ext_vector_type(4))) float f32x4;

__device__ __forceinline__ unsigned short f2bf(float f) {
  unsigned u = __builtin_bit_cast(unsigned, f);
  u += 0x7FFFu + ((u >> 16) & 1u);
  return (unsigned short)(u >> 16);
}
__device__ __forceinline__ unsigned pk2(float a, float b) {
  return (unsigned)f2bf(a) | ((unsigned)f2bf(b) << 16);
}
__device__ __forceinline__ float bf2f(unsigned short u) {
  return __builtin_bit_cast(float, ((unsigned)u) << 16);
}

__device__ __forceinline__ void gl16(const void* g, void* s) {
  __builtin_amdgcn_global_load_lds(
      (const __attribute__((address_space(1))) unsigned int*)g,
      (__attribute__((address_space(3))) unsigned int*)s, 16, 0, 0);
}

#define WAITV(N)  asm volatile("s_waitcnt vmcnt(" #N ")" ::: "memory")
#define WAITL0    asm volatile("s_waitcnt lgkmcnt(0)" ::: "memory")
#define SBAR      __builtin_amdgcn_s_barrier()
#define SCHED0    __builtin_amdgcn_sched_barrier(0)

// ---------------- split conversion (+ fused counts zeroing) ----------------

__global__ __launch_bounds__(256) void cvt_split_kernel(const float* __restrict__ x,
    const float* __restrict__ Wr,
    unsigned short* __restrict__ xhi, unsigned short* __restrict__ xlo,
    unsigned short* __restrict__ whi, unsigned short* __restrict__ wlo,
    int* __restrict__ counts)
{
  if (blockIdx.x == 0 && threadIdx.x < 64) counts[threadIdx.x] = 0;
  const float* src; unsigned short* dhi; unsigned short* dlo; long i;
  long bid = blockIdx.x;
  if (bid < 3072) { src = x;  dhi = xhi; dlo = xlo; i = (bid * 256 + threadIdx.x) * 8; }
  else            { src = Wr; dhi = whi; dlo = wlo; i = ((bid - 3072) * 256 + threadIdx.x) * 8; }
  float4 a = *(const float4*)(src + i);
  float4 b = *(const float4*)(src + i + 4);
  float f[8] = {a.x, a.y, a.z, a.w, b.x, b.y, b.z, b.w};
  unsigned short h[8], l[8];
  #pragma unroll
  for (int j = 0; j < 8; ++j) {
    h[j] = f2bf(f[j]);
    l[j] = f2bf(f[j] - bf2f(h[j]));
  }
  uint4 ph, pl;
  ph.x = (unsigned)h[0] | ((unsigned)h[1] << 16);
  ph.y = (unsigned)h[2] | ((unsigned)h[3] << 16);
  ph.z = (unsigned)h[4] | ((unsigned)h[5] << 16);
  ph.w = (unsigned)h[6] | ((unsigned)h[7] << 16);
  pl.x = (unsigned)l[0] | ((unsigned)l[1] << 16);
  pl.y = (unsigned)l[2] | ((unsigned)l[3] << 16);
  pl.z = (unsigned)l[4] | ((unsigned)l[5] << 16);
  pl.w = (unsigned)l[6] | ((unsigned)l[7] << 16);
  *(uint4*)(dhi + i) = ph;
  *(uint4*)(dlo + i) = pl;
}

// ---------------- router v5: split-bf16 MFMA GEMM + in-kernel top-2 ----------------

__global__ __launch_bounds__(256) void router_kernel(
    const unsigned short* __restrict__ xhi, const unsigned short* __restrict__ xlo,
    const unsigned short* __restrict__ whi, const unsigned short* __restrict__ wlo,
    int* __restrict__ topidx, float* __restrict__ topw, int* __restrict__ counts)
{
  __shared__ unsigned short lds[8 * 4096];
  const int tid  = threadIdx.x;
  const int lane = tid & 63;
  const int wv   = tid >> 6;
  const int t0   = blockIdx.x * 64;

  const int lslot = (lane & 7) ^ (lane >> 3);
  const unsigned short* gsrc[4][2];
  #pragma unroll
  for (int j = 0; j < 2; ++j) {
    int r = (wv * 2 + j) * 8 + (lane >> 3);
    gsrc[0][j] = xhi + (long)(t0 + r) * D_MODEL + lslot * 8;
    gsrc[1][j] = xlo + (long)(t0 + r) * D_MODEL + lslot * 8;
    gsrc[2][j] = whi + (long)r * D_MODEL + lslot * 8;
    gsrc[3][j] = wlo + (long)r * D_MODEL + lslot * 8;
  }

  auto ISSUE = [&](int t, int b) {
    const int k0 = t * 64;
    SCHED0;
    #pragma unroll
    for (int tile = 0; tile < 4; ++tile)
      #pragma unroll
      for (int j = 0; j < 2; ++j)
        gl16(gsrc[tile][j] + k0, &lds[(b * 4 + tile) * 4096 + (wv * 2 + j) * 512]);
    SCHED0;
  };

  f32x4 acc[4];
  #pragma unroll
  for (int i = 0; i < 4; ++i) acc[i] = (f32x4)0.f;

  const int arow = wv * 16 + (lane & 15);

  auto COMPUTE = [&](int b) {
    const unsigned short* Ah = &lds[(b * 4 + 0) * 4096];
    const unsigned short* Al = &lds[(b * 4 + 1) * 4096];
    const unsigned short* Bh = &lds[(b * 4 + 2) * 4096];
    const unsigned short* Bl = &lds[(b * 4 + 3) * 4096];
    #pragma unroll
    for (int ks = 0; ks < 2; ++ks) {
      int pa = (ks * 4 + (lane >> 4)) ^ (arow & 7);
      short8 ah = *(const short8*)(Ah + arow * 64 + pa * 8);
      short8 al = *(const short8*)(Al + arow * 64 + pa * 8);
      short8 bh[4], bl[4];
      #pragma unroll
      for (int ni = 0; ni < 4; ++ni) {
        int br = ni * 16 + (lane & 15);
        int pb = (ks * 4 + (lane >> 4)) ^ (br & 7);
        bh[ni] = *(const short8*)(Bh + br * 64 + pb * 8);
        bl[ni] = *(const short8*)(Bl + br * 64 + pb * 8);
      }
      #pragma unroll
      for (int ni = 0; ni < 4; ++ni) {
        acc[ni] = __builtin_amdgcn_mfma_f32_16x16x32_bf16(ah, bh[ni], acc[ni], 0, 0, 0);
        acc[ni] = __builtin_amdgcn_mfma_f32_16x16x32_bf16(ah, bl[ni], acc[ni], 0, 0, 0);
        acc[ni] = __builtin_amdgcn_mfma_f32_16x16x32_bf16(al, bh[ni], acc[ni], 0, 0, 0);
      }
    }
  };

  ISSUE(0, 0);
  ISSUE(1, 1);
  WAITV(8);
  SBAR;

  #pragma unroll 1
  for (int t = 0; t < NT1; t += 2) {
    COMPUTE(0);
    SBAR;
    if (t + 2 < NT1) { ISSUE(t + 2, 0); WAITV(8); }
    else             { WAITV(0); }
    SBAR;
    COMPUTE(1);
    SBAR;
    if (t + 2 < NT1) {
      if (t + 3 < NT1) { ISSUE(t + 3, 1); WAITV(8); }
      else             { WAITV(0); }
      SBAR;
    }
  }

  float* lgl = (float*)lds;           // [64][66]
  #pragma unroll
  for (int ni = 0; ni < 4; ++ni)
    #pragma unroll
    for (int rg = 0; rg < 4; ++rg) {
      int tok = wv * 16 + (lane >> 4) * 4 + rg;
      int e   = ni * 16 + (lane & 15);
      lgl[tok * 66 + e] = acc[ni][rg];
    }
  __syncthreads();

  for (int i = 0; i < 16; ++i) {
    const int tl = wv * 16 + i;
    float v = lgl[tl * 66 + lane];
    float v0 = v; int e0 = lane;
    #pragma unroll
    for (int off = 32; off > 0; off >>= 1) {
      float ov = __shfl_xor(v0, off);
      int   oe = __shfl_xor(e0, off);
      if (ov > v0 || (ov == v0 && oe < e0)) { v0 = ov; e0 = oe; }
    }
    float v1 = (lane == e0) ? -3.0e38f : v;
    int e1 = lane;
    #pragma unroll
    for (int off = 32; off > 0; off >>= 1) {
      float ov = __shfl_xor(v1, off);
      int   oe = __shfl_xor(e1, off);
      if (ov > v1 || (ov == v1 && oe < e1)) { v1 = ov; e1 = oe; }
    }
    if (lane == 0) {
      int tt = t0 + tl;
      float w0 = 1.f / (1.f + expf(v1 - v0));
      topidx[tt * 2]     = e0;
      topidx[tt * 2 + 1] = e1;
      topw[tt * 2]       = w0;
      topw[tt * 2 + 1]   = 1.f - w0;
      atomicAdd(&counts[e0], 1);
      atomicAdd(&counts[e1], 1);
    }
  }
}

// ---------------- scan + scatter ----------------

__global__ void scan_kernel(const int* __restrict__ counts, int* __restrict__ offs,
                            int* __restrict__ cursor)
{
  int e = threadIdx.x;
  int c = counts[e];
  int xx = c;
  #pragma unroll
  for (int off = 1; off < 64; off <<= 1) {
    int y = __shfl_up(xx, off);
    if (e >= off) xx += y;
  }
  offs[e + 1] = xx;
  if (e == 0) offs[0] = 0;
  cursor[e] = 0;
}

__global__ void scatter_kernel(const int* __restrict__ topidx, const float* __restrict__ topw,
    const int* __restrict__ offs, int* __restrict__ cursor,
    int* __restrict__ perm, float* __restrict__ wgt, int* __restrict__ tok2slot)
{
  int t = blockIdx.x * blockDim.x + threadIdx.x;
  if (t >= NTOK) return;
  #pragma unroll
  for (int k = 0; k < 2; ++k) {
    int e = topidx[t * 2 + k];
    float w = topw[t * 2 + k];
    int pos = atomicAdd(&cursor[e], 1);
    int slot = offs[e] + pos;
    perm[slot] = t;
    wgt[slot] = w;
    tok2slot[t * 2 + k] = slot;
  }
}

// ---- pipelined step, de-walled: B-write overlapped with ks1 compute ----
#define FS(T, AB, BRI, BRW, KNT)                                    \
  {                                                                 \
    CKS(Abuf[AB], Bbuf[AB], 0);                                     \
    if ((T) + 1 < (KNT)) {                                          \
      if ((T) + 2 < (KNT)) { WAITV(10); } else { WAITV(6); }        \
      WRITE_B(BRW, Bbuf[(AB) ^ 1]);                                 \
    }                                                               \
    CKS(Abuf[AB], Bbuf[AB], 1);                                     \
    SBAR;                                                           \
    if ((T) + 2 < (KNT)) ISSUEA((T) + 2, Abuf[AB]);                 \
    if ((T) + 3 < (KNT)) ISSUEB((T) + 3, BRI);                      \
    if ((T) + 3 < (KNT))      { WAITV(14); }                        \
    else if ((T) + 2 < (KNT)) { WAITV(10); }                        \
    else                      { WAITV(0);  }                        \
    WAITL0;                                                         \
    SBAR;                                                           \
  }

// ---------------- ffn1: 256-thread, B depth-3, XCD-swizzled grid ----------------

__global__ __launch_bounds__(256, 2) void ffn1_kernel(
    const unsigned short* __restrict__ xb, const float* __restrict__ W1,
    const int* __restrict__ offs, const int* __restrict__ perm,
    const float* __restrict__ wgt, unsigned short* __restrict__ hbuf)
{
  const int bid = blockIdx.x;
  const int e   = (bid & 7) * 8 + (bid >> 6);
  const int nc  = (bid >> 3) & 7;
  const int cnt = offs[e + 1] - offs[e];
  if (cnt == 0) return;

  __shared__ unsigned short Abuf[2][MT * 64];
  __shared__ unsigned short Bbuf[2][64 * 64];

  const int tid  = threadIdx.x;
  const int lane = tid & 63;
  const int wv   = tid >> 6;

  const int qB = tid & 15;
  const int rB = tid >> 4;
  const float* bptr[4];
  #pragma unroll
  for (int p = 0; p < 4; ++p)
    bptr[p] = W1 + ((long)e * D_HID + nc * 64 + p * 16 + rB) * D_MODEL + qB * 4;

  int arow[3], brow[4];
  int physA[2][3], physB[2][4];
  #pragma unroll
  for (int mi = 0; mi < 3; ++mi) {
    arow[mi] = wv * 48 + mi * 16 + (lane & 15);
    #pragma unroll
    for (int ks = 0; ks < 2; ++ks)
      physA[ks][mi] = (ks * 4 + (lane >> 4)) ^ (arow[mi] & 7);
  }
  #pragma unroll
  for (int ni = 0; ni < 4; ++ni) {
    brow[ni] = ni * 16 + (lane & 15);
    #pragma unroll
    for (int ks = 0; ks < 2; ++ks)
      physB[ks][ni] = (ks * 4 + (lane >> 4)) ^ (brow[ni] & 7);
  }
  const int lslot = (lane & 7) ^ (lane >> 3);

  for (int m0 = 0; m0 < cnt; m0 += MT) {
    const int base = offs[e] + m0;
    const int mcnt = min(MT, cnt - m0);

    const unsigned short* gptrA[6];
    #pragma unroll
    for (int j = 0; j < 6; ++j) {
      int pr = (wv * 6 + j) * 8 + (lane >> 3);
      if (pr >= mcnt) pr = mcnt - 1;
      gptrA[j] = xb + (long)perm[base + pr] * D_MODEL + lslot * 8;
    }

    f32x4 acc[3][4];
    #pragma unroll
    for (int i = 0; i < 3; ++i)
      #pragma unroll
      for (int j = 0; j < 4; ++j) acc[i][j] = (f32x4)0.f;

    float4 br0[4], br1[4], br2[4];

    auto ISSUEA = [&](int t, unsigned short* Ab) {
      const int k0 = t * 64;
      #pragma unroll
      for (int j = 0; j < 6; ++j)
        gl16(gptrA[j] + k0, Ab + (wv * 6 + j) * 512);
    };
    auto ISSUEB = [&](int t, float4* br) {
      const int k0 = t * 64;
      #pragma unroll
      for (int p = 0; p < 4; ++p) br[p] = *(const float4*)(bptr[p] + k0);
    };
    auto WRITE_B = [&](const float4* br, unsigned short* B_) {
      #pragma unroll
      for (int p = 0; p < 4; ++p) {
        int rr = p * 16 + rB;
        unsigned lo = pk2(br[p].x, br[p].y);
        unsigned hi = pk2(br[p].z, br[p].w);
        int ph = (qB >> 1) ^ (rr & 7);
        *(uint2*)(B_ + rr * 64 + ph * 8 + (qB & 1) * 4) = make_uint2(lo, hi);
      }
    };
    auto CKS = [&](const unsigned short* A_, const unsigned short* B_, int ks) {
      short8 a[3], bb[4];
      #pragma unroll
      for (int mi = 0; mi < 3; ++mi)
        a[mi] = *(const short8*)(A_ + arow[mi] * 64 + physA[ks][mi] * 8);
      #pragma unroll
      for (int ni = 0; ni < 4; ++ni)
        bb[ni] = *(const short8*)(B_ + brow[ni] * 64 + physB[ks][ni] * 8);
      #pragma unroll
      for (int mi = 0; mi < 3; ++mi)
        #pragma unroll
        for (int ni = 0; ni < 4; ++ni)
          acc[mi][ni] = __builtin_amdgcn_mfma_f32_16x16x32_bf16(a[mi], bb[ni], acc[mi][ni], 0, 0, 0);
    };

    // prologue (FIFO order matches steady state: ...B1, A1, B2 newest)
    ISSUEA(0, Abuf[0]); ISSUEB(0, br0);
    ISSUEB(1, br1);
    ISSUEA(1, Abuf[1]); ISSUEB(2, br2);
    WAITV(14);                       // newest 14 = B1,A1,B2 -> A0,B0 landed
    WRITE_B(br0, Bbuf[0]);
    WAITL0;
    SBAR;

    #pragma unroll 1
    for (int t = 0; t < NT1; t += 6) {
      FS(t + 0, 0, br0, br1, NT1);
      FS(t + 1, 1, br1, br2, NT1);
      FS(t + 2, 0, br2, br0, NT1);
      FS(t + 3, 1, br0, br1, NT1);
      FS(t + 4, 0, br1, br2, NT1);
      FS(t + 5, 1, br2, br0, NT1);
    }

    // epilogue: SiLU*gate -> bf16 via LDS transpose -> coalesced uint4 stores
    unsigned short* fds = &Abuf[0][0];
    const int rsub = (lane >> 4) * 4;
    const int csub = lane & 15;
    #pragma unroll
    for (int mi = 0; mi < 3; ++mi) {
      #pragma unroll
      for (int rg = 0; rg < 4; ++rg) {
        int r = wv * 48 + mi * 16 + rsub + rg;
        float wt = (r < mcnt) ? wgt[base + r] : 0.f;
        #pragma unroll
        for (int ni = 0; ni < 4; ++ni) {
          float v = acc[mi][ni][rg];
          float sv = v / (1.f + __expf(-v)) * wt;
          fds[r * 64 + ni * 16 + csub] = f2bf(sv);
        }
      }
    }
    __syncthreads();
    #pragma unroll
    for (int q = 0; q < 6; ++q) {
      int idx = q * 256 + tid;
      int row = idx >> 3, c8 = idx & 7;
      if (row < mcnt)
        *(uint4*)(hbuf + (long)(base + row) * D_HID + nc * 64 + c8 * 8) =
            *(const uint4*)(fds + row * 64 + c8 * 8);
    }
    __syncthreads();
  }
}

// ---------------- ffn2: same structure, XCD-swizzled grid, A = hbuf ----------------

__global__ __launch_bounds__(256, 2) void ffn2_kernel(
    const unsigned short* __restrict__ hbuf, const float* __restrict__ W2,
    const int* __restrict__ offs, unsigned short* __restrict__ sbuf)
{
  const int bid = blockIdx.x;
  const int j   = bid >> 3;
  const int e   = (bid & 7) * 8 + j / 24;
  const int nc  = j % 24;
  const int cnt = offs[e + 1] - offs[e];
  if (cnt == 0) return;

  __shared__ unsigned short Abuf[2][MT * 64];
  __shared__ unsigned short Bbuf[2][64 * 64];

  const int tid  = threadIdx.x;
  const int lane = tid & 63;
  const int wv   = tid >> 6;

  const int qB = tid & 15;
  const int rB = tid >> 4;
  const float* bptr[4];
  #pragma unroll
  for (int p = 0; p < 4; ++p)
    bptr[p] = W2 + ((long)e * D_MODEL + nc * 64 + p * 16 + rB) * D_HID + qB * 4;

  int arow[3], brow[4];
  int physA[2][3], physB[2][4];
  #pragma unroll
  for (int mi = 0; mi < 3; ++mi) {
    arow[mi] = wv * 48 + mi * 16 + (lane & 15);
    #pragma unroll
    for (int ks = 0; ks < 2; ++ks)
      physA[ks][mi] = (ks * 4 + (lane >> 4)) ^ (arow[mi] & 7);
  }
  #pragma unroll
  for (int ni = 0; ni < 4; ++ni) {
    brow[ni] = ni * 16 + (lane & 15);
    #pragma unroll
    for (int ks = 0; ks < 2; ++ks)
      physB[ks][ni] = (ks * 4 + (lane >> 4)) ^ (brow[ni] & 7);
  }
  const int lslot = (lane & 7) ^ (lane >> 3);

  for (int m0 = 0; m0 < cnt; m0 += MT) {
    const int base = offs[e] + m0;
    const int mcnt = min(MT, cnt - m0);

    const unsigned short* gptrA[6];
    #pragma unroll
    for (int j2 = 0; j2 < 6; ++j2) {
      int pr = (wv * 6 + j2) * 8 + (lane >> 3);
      if (pr >= mcnt) pr = mcnt - 1;
      gptrA[j2] = hbuf + (long)(base + pr) * D_HID + lslot * 8;
    }

    f32x4 acc[3][4];
    #pragma unroll
    for (int i = 0; i < 3; ++i)
      #pragma unroll
      for (int j2 = 0; j2 < 4; ++j2) acc[i][j2] = (f32x4)0.f;

    float4 br0[4], br1[4], br2[4];

    auto ISSUEA = [&](int t, unsigned short* Ab) {
      const int k0 = t * 64;
      #pragma unroll
      for (int j2 = 0; j2 < 6; ++j2)
        gl16(gptrA[j2] + k0, Ab + (wv * 6 + j2) * 512);
    };
    auto ISSUEB = [&](int t, float4* br) {
      const int k0 = t * 64;
      #pragma unroll
      for (int p = 0; p < 4; ++p) br[p] = *(const float4*)(bptr[p] + k0);
    };
    auto WRITE_B = [&](const float4* br, unsigned short* B_) {
      #pragma unroll
      for (int p = 0; p < 4; ++p) {
        int rr = p * 16 + rB;
        unsigned lo = pk2(br[p].x, br[p].y);
        unsigned hi = pk2(br[p].z, br[p].w);
        int ph = (qB >> 1) ^ (rr & 7);
        *(uint2*)(B_ + rr * 64 + ph * 8 + (qB & 1) * 4) = make_uint2(lo, hi);
      }
    };
    auto CKS = [&](const unsigned short* A_, const unsigned short* B_, int ks) {
      short8 a[3], bb[4];
      #pragma unroll
      for (int mi = 0; mi < 3; ++mi)
        a[mi] = *(const short8*)(A_ + arow[mi] * 64 + physA[ks][mi] * 8);
      #pragma unroll
      for (int ni = 0; ni < 4; ++ni)
        bb[ni] = *(const short8*)(B_ + brow[ni] * 64 + physB[ks][ni] * 8);
      #pragma unroll
      for (int mi = 0; mi < 3; ++mi)
        #pragma unroll
        for (int ni = 0; ni < 4; ++ni)
          acc[mi][ni] = __builtin_amdgcn_mfma_f32_16x16x32_bf16(a[mi], bb[ni], acc[mi][ni], 0, 0, 0);
    };

    ISSUEA(0, Abuf[0]); ISSUEB(0, br0);
    ISSUEB(1, br1);
    ISSUEA(1, Abuf[1]); ISSUEB(2, br2);
    WAITV(14);
    WRITE_B(br0, Bbuf[0]);
    WAITL0;
    SBAR;

    // NT2 = 8, fully unrolled
    FS(0, 0, br0, br1, NT2);
    FS(1, 1, br1, br2, NT2);
    FS(2, 0, br2, br0, NT2);
    FS(3, 1, br0, br1, NT2);
    FS(4, 0, br1, br2, NT2);
    FS(5, 1, br2, br0, NT2);
    FS(6, 0, br0, br1, NT2);
    FS(7, 1, br1, br2, NT2);

    // epilogue: bf16 transpose via LDS -> coalesced uint4 stores
    unsigned short* fds = &Abuf[0][0];
    const int rsub = (lane >> 4) * 4;
    const int csub = lane & 15;
    #pragma unroll
    for (int mi = 0; mi < 3; ++mi) {
      #pragma unroll
      for (int rg = 0; rg < 4; ++rg) {
        int r = wv * 48 + mi * 16 + rsub + rg;
        #pragma unroll
        for (int ni = 0; ni < 4; ++ni)
          fds[r * 64 + ni * 16 + csub] = f2bf(acc[mi][ni][rg]);
      }
    }
    __syncthreads();
    #pragma unroll
    for (int q = 0; q < 6; ++q) {
      int idx = q * 256 + tid;
      int row = idx >> 3, c8 = idx & 7;
      if (row < mcnt)
        *(uint4*)(sbuf + (long)(base + row) * D_MODEL + nc * 64 + c8 * 8) =
            *(const uint4*)(fds + row * 64 + c8 * 8);
    }
    __syncthreads();
  }
}

// ---------------- gather + LayerNorm (bf16 sbuf) ----------------

__global__ __launch_bounds__(192) void ln_kernel(const unsigned short* __restrict__ sbuf,
    const int* __restrict__ tok2slot, float* __restrict__ out,
    const float* __restrict__ gamma, const float* __restrict__ beta)
{
  const int tid = threadIdx.x;
  const int t = blockIdx.x;
  const long r0 = (long)tok2slot[t * 2]     * D_MODEL;
  const long r1 = (long)tok2slot[t * 2 + 1] * D_MODEL;

  uint4 u0 = *(const uint4*)(sbuf + r0 + tid * 8);
  uint4 u1 = *(const uint4*)(sbuf + r1 + tid * 8);
  float v[8];
  {
    const unsigned* p0 = &u0.x;
    const unsigned* p1 = &u1.x;
    #pragma unroll
    for (int i = 0; i < 4; ++i) {
      v[i * 2]     = bf2f((unsigned short)(p0[i] & 0xFFFFu)) + bf2f((unsigned short)(p1[i] & 0xFFFFu));
      v[i * 2 + 1] = bf2f((unsigned short)(p0[i] >> 16))     + bf2f((unsigned short)(p1[i] >> 16));
    }
  }

  float s = 0.f, sq = 0.f;
  #pragma unroll
  for (int i = 0; i < 8; ++i) { s += v[i]; sq += v[i] * v[i]; }
  #pragma unroll
  for (int off = 32; off > 0; off >>= 1) {
    s  += __shfl_xor(s, off);
    sq += __shfl_xor(sq, off);
  }
  __shared__ float ss[3], sqs[3];
  int wv = tid >> 6;
  if ((tid & 63) == 0) { ss[wv] = s; sqs[wv] = sq; }
  __syncthreads();
  s  = ss[0] + ss[1] + ss[2];
  sq = sqs[0] + sqs[1] + sqs[2];
  const float inv = 1.f / (float)D_MODEL;
  float mu  = s * inv;
  float var = sq * inv - mu * mu;
  float rs  = 1.f / sqrtf(var + 1e-5f);

  float4 g1 = *(const float4*)(gamma + tid * 8);
  float4 g2 = *(const float4*)(gamma + tid * 8 + 4);
  float4 b1v = *(const float4*)(beta + tid * 8);
  float4 b2v = *(const float4*)(beta + tid * 8 + 4);
  float4 a, b;
  a.x = (v[0] - mu) * rs * g1.x + b1v.x;
  a.y = (v[1] - mu) * rs * g1.y + b1v.y;
  a.z = (v[2] - mu) * rs * g1.z + b1v.z;
  a.w = (v[3] - mu) * rs * g1.w + b1v.w;
  b.x = (v[4] - mu) * rs * g2.x + b2v.x;
  b.y = (v[5] - mu) * rs * g2.y + b2v.y;
  b.z = (v[6] - mu) * rs * g2.z + b2v.z;
  b.w = (v[7] - mu) * rs * g2.w + b2v.w;
  float* row = out + (long)t * D_MODEL;
  *(float4*)(row + tid * 8)     = a;
  *(float4*)(row + tid * 8 + 4) = b;
}

// ---------------- launch ----------------

extern "C" void kernel_launch(void* const* d_in, const int* in_sizes, int n_in,
                              void* d_out, int out_size, void* d_ws, size_t ws_size,
                              hipStream_t stream) {
  const float* x     = (const float*)d_in[0];
  const float* Wr    = (const float*)d_in[1];
  const float* W1    = (const float*)d_in[2];
  const float* W2    = (const float*)d_in[3];
  const float* gamma = (const float*)d_in[4];
  const float* beta  = (const float*)d_in[5];
  float* out = (float*)d_out;

  char* ws = (char*)d_ws;
  unsigned short* xhi    = (unsigned short*)(ws + 0);          // 12,582,912
  unsigned short* xlo    = (unsigned short*)(ws + 12582912);   // 12,582,912
  unsigned short* hbuf   = (unsigned short*)(ws + 25165824);   //  8,388,608
  unsigned short* sbuf   = (unsigned short*)(ws + 33554432);   // 25,165,824
  unsigned short* whi    = (unsigned short*)(ws + 58720256);   //    196,608
  unsigned short* wlo    = (unsigned short*)(ws + 58916864);   //    196,608
  int*   topidx   = (int*)  (ws + 59113472);                   //     32,768
  float* topw     = (float*)(ws + 59146240);                   //     32,768
  int*   counts   = (int*)  (ws + 59179008);                   //        256
  int*   cursor   = (int*)  (ws + 59179264);                   //        256
  int*   offs     = (int*)  (ws + 59179520);                   //        512
  int*   tok2slot = (int*)  (ws + 59180032);                   //     32,768
  int*   perm     = (int*)  (ws + 59212800);                   //     32,768
  float* wgt      = (float*)(ws + 59245568);                   //     32,768

  hipLaunchKernelGGL(cvt_split_kernel, dim3(3120), dim3(256), 0, stream, x, Wr, xhi, xlo, whi, wlo, counts);
  hipLaunchKernelGGL(router_kernel, dim3(NTOK / 64), dim3(256), 0, stream, xhi, xlo, whi, wlo, topidx, topw, counts);
  hipLaunchKernelGGL(scan_kernel, dim3(1), dim3(64), 0, stream, counts, offs, cursor);
  hipLaunchKernelGGL(scatter_kernel, dim3(NTOK / 256), dim3(256), 0, stream, topidx, topw, offs, cursor, perm, wgt, tok2slot);
  hipLaunchKernelGGL(ffn1_kernel, dim3(512), dim3(256), 0, stream, xhi, W1, offs, perm, wgt, hbuf);
  hipLaunchKernelGGL(ffn2_kernel, dim3(1536), dim3(256), 0, stream, hbuf, W2, offs, sbuf);
  hipLaunchKernelGGL(ln_kernel, dim3(NTOK), dim3(192), 0, stream, sbuf, tok2slot, out, gamma, beta);
}